// Round 1
// 387.587 us; speedup vs baseline: 1.0250x; 1.0250x over previous
//
#include <hip/hip_runtime.h>

// NTM cell forward. f32 in/out, bf16 MFMA for all large GEMMs (tolerance is bf16-grade).
// B=2048 N=256 M=64 U=512 IN=10 SHIFT=1 CLIP=20
// Outputs flat (f32): y_t[B*512] | m_t[B*256*64] | R_t[B*64] | w_read[B*256] | w_write[B*256]

using u16   = unsigned short;
using bfrag = __attribute__((ext_vector_type(8))) short;   // 8 bf16 (4 VGPRs)
using f4    = __attribute__((ext_vector_type(4))) float;   // MFMA accumulator

__device__ __forceinline__ float bf2f(u16 s){ union{float f;unsigned u;}v; v.u=((unsigned)s)<<16; return v.f; }
__device__ __forceinline__ u16 f2bf(float f){ union{float f;unsigned u;}v; v.f=f; unsigned r=v.u+0x7fffu+((v.u>>16)&1u); return (u16)(r>>16); }
__device__ __forceinline__ void bfpair(unsigned pr, float&a, float&b){ union{float f;unsigned u;}x,y; x.u=pr<<16; y.u=pr&0xffff0000u; a=x.f; b=y.f; }
__device__ __forceinline__ unsigned packbf(float a, float b){ return (unsigned)f2bf(a) | ((unsigned)f2bf(b)<<16); }
__device__ __forceinline__ float sigm(float x){ return 1.f/(1.f+expf(-x)); }
__device__ __forceinline__ float softplus_(float x){ return fmaxf(x,0.f)+log1pf(expf(-fabsf(x))); }

// async global->LDS, 16B per lane; lptr must be wave-uniform (HW adds lane*16)
__device__ __forceinline__ void gld16(const u16* g, u16* l){
    __builtin_amdgcn_global_load_lds((const __attribute__((address_space(1))) unsigned*)g,
                                     (__attribute__((address_space(3))) unsigned*)l, 16, 0, 0);
}

// ======================= weight transpose/convert kernels =======================
// dst layout: Wt[n][k] bf16 (so A and B MFMA fragments load identically, gemm_bt style)

__global__ __launch_bounds__(256) void k_wt_lstm(const float* __restrict__ Wx, const float* __restrict__ Wh,
                                                 u16* __restrict__ Wt){
    __shared__ float t[32][33];
    int n0 = blockIdx.x*32, k0 = blockIdx.y*32;           // n<2048, k<1056
    int tx = threadIdx.x & 31, ty = threadIdx.x >> 5;     // ty 0..7
    #pragma unroll
    for(int r=0;r<4;r++){
        int k = k0 + ty*4 + r, n = n0 + tx;
        float v;
        if(k < 522)       v = Wx[k*2048 + n];
        else if(k < 1034) v = Wh[(k-522)*2048 + n];
        else              v = 0.f;
        t[ty*4+r][tx] = v;
    }
    __syncthreads();
    #pragma unroll
    for(int r=0;r<4;r++){
        int n = n0 + ty*4 + r, k = k0 + tx;
        Wt[n*1056 + k] = f2bf(t[tx][ty*4+r]);
    }
}

__global__ __launch_bounds__(256) void k_wt_heads(const float* __restrict__ Wr, const float* __restrict__ Ww,
                                                  u16* __restrict__ Wt){
    __shared__ float t[32][33];
    int n0 = blockIdx.x*32, k0 = blockIdx.y*32;           // n<384 (pad), k<512
    int tx = threadIdx.x & 31, ty = threadIdx.x >> 5;
    #pragma unroll
    for(int r=0;r<4;r++){
        int k = k0 + ty*4 + r, n = n0 + tx;
        float v;
        if(n < 70)        v = Wr[k*70 + n];
        else if(n < 268)  v = Ww[k*198 + (n-70)];
        else              v = 0.f;
        t[ty*4+r][tx] = v;
    }
    __syncthreads();
    #pragma unroll
    for(int r=0;r<4;r++){
        int n = n0 + ty*4 + r, k = k0 + tx;
        Wt[n*512 + k] = f2bf(t[tx][ty*4+r]);
    }
}

__global__ __launch_bounds__(256) void k_wt_out(const float* __restrict__ Wo, u16* __restrict__ Wt){
    __shared__ float t[32][33];
    int n0 = blockIdx.x*32, k0 = blockIdx.y*32;           // n<512, k<576
    int tx = threadIdx.x & 31, ty = threadIdx.x >> 5;
    #pragma unroll
    for(int r=0;r<4;r++){
        int k = k0 + ty*4 + r, n = n0 + tx;
        t[ty*4+r][tx] = Wo[k*512 + n];
    }
    __syncthreads();
    #pragma unroll
    for(int r=0;r<4;r++){
        int n = n0 + ty*4 + r, k = k0 + tx;
        Wt[n*576 + k] = f2bf(t[tx][ty*4+r]);
    }
}

// ======================= A-matrix build: [x | hprep | H0 | 0pad], bf16, lda=1056 =======================
__global__ __launch_bounds__(256) void k_abuild(const float* __restrict__ x, const float* __restrict__ H0,
                                                const float* __restrict__ R0, const float* __restrict__ Wprep,
                                                const float* __restrict__ bprep, u16* __restrict__ A){
    int flat = blockIdx.x*256 + threadIdx.x;   // B*512
    int b = flat >> 9, u = flat & 511;
    u16* Ab = A + (size_t)b*1056;
    // hprep = R0 @ Wprep + bprep
    float acc = bprep[u];
    const float* r = R0 + b*64;
    #pragma unroll 8
    for(int m=0;m<64;m++) acc += r[m] * Wprep[m*512+u];
    Ab[10+u] = f2bf(acc);
    Ab[522+u] = f2bf(H0[b*512+u]);
    if(u<10) Ab[u] = f2bf(x[b*10+u]);
    if(u<22) Ab[1034+u] = 0;                   // zero K-pad 1034..1055
}

// ======================= MFMA GEMM core: 128x128 C tile, BK=32 =======================
// A: M x K row-major bf16 (lda), Bt: N x K row-major bf16 (ldb). 256 threads = 4 waves,
// wave (wr,wc) owns 64x64 = 4x4 of 16x16x32 MFMAs. m97 2-barrier structure.
__device__ __forceinline__ void gemm128(const u16* __restrict__ A, int lda,
                                        const u16* __restrict__ Bt, int ldb,
                                        int bm, int bn, int kiters,
                                        u16* Al, u16* Bl, f4 acc[4][4]){
    int tid = threadIdx.x, w = tid>>6, lane = tid&63, quad = lane>>4, l16 = lane&15;
    int wr = w>>1, wc = w&1;
    f4 z4 = {0.f,0.f,0.f,0.f};
    #pragma unroll
    for(int i=0;i<4;i++)
        #pragma unroll
        for(int j=0;j<4;j++) acc[i][j] = z4;
    // staging chunks: 512 x 16B per tile, 2 per thread; chunk c -> row c>>2, kchunk c&3
    int rA0 = tid>>2, kc = tid&3;        // q=0 rows 0..63
    int rA1 = rA0 + 64;                  // q=1 rows 64..127
    const u16* ga0 = A  + (size_t)(bm+rA0)*lda + kc*8;
    const u16* ga1 = A  + (size_t)(bm+rA1)*lda + kc*8;
    const u16* gb0 = Bt + (size_t)(bn+rA0)*ldb + kc*8;
    const u16* gb1 = Bt + (size_t)(bn+rA1)*ldb + kc*8;
    u16* lA0 = Al + (w*64)*8;            // wave-uniform LDS bases (chunks w*64.., +lane*16B by HW)
    u16* lA1 = Al + (256 + w*64)*8;
    u16* lB0 = Bl + (w*64)*8;
    u16* lB1 = Bl + (256 + w*64)*8;
    for(int kt=0; kt<kiters; kt++){
        __syncthreads();
        gld16(ga0, lA0); gld16(ga1, lA1);
        gld16(gb0, lB0); gld16(gb1, lB1);
        ga0 += 32; ga1 += 32; gb0 += 32; gb1 += 32;
        __syncthreads();
        bfrag af[4], bf[4];
        #pragma unroll
        for(int i=0;i<4;i++) af[i] = *(const bfrag*)&Al[(wr*64 + i*16 + l16)*32 + quad*8];
        #pragma unroll
        for(int j=0;j<4;j++) bf[j] = *(const bfrag*)&Bl[(wc*64 + j*16 + l16)*32 + quad*8];
        #pragma unroll
        for(int i=0;i<4;i++)
            #pragma unroll
            for(int j=0;j<4;j++)
                acc[i][j] = __builtin_amdgcn_mfma_f32_16x16x32_bf16(af[i], bf[j], acc[i][j], 0, 0, 0);
    }
}
// C/D mapping (m89-verified): col = lane&15, row = quad*4 + reg.

// ------------- GEMM 1: z = A @ Wt_lstm^T  (2048 x 2048, K=1056), raw f32 store -------------
__global__ __launch_bounds__(256) void k_gemm_lstm(const u16* __restrict__ A, const u16* __restrict__ Wt,
                                                   float* __restrict__ z){
    __shared__ u16 Al[128*32], Bl[128*32];
    f4 acc[4][4];
    int bm = blockIdx.x*128, bn = blockIdx.y*128;
    gemm128(A, 1056, Wt, 1056, bm, bn, 33, Al, Bl, acc);
    int lane = threadIdx.x&63, quad = lane>>4, l16 = lane&15, w = threadIdx.x>>6;
    int wr = w>>1, wc = w&1;
    #pragma unroll
    for(int i=0;i<4;i++){
        #pragma unroll
        for(int j=0;j<4;j++){
            int col = bn + wc*64 + j*16 + l16;
            #pragma unroll
            for(int r=0;r<4;r++){
                int row = bm + wr*64 + i*16 + quad*4 + r;
                z[(size_t)row*2048 + col] = acc[i][j][r];
            }
        }
    }
}

// ------------- gates: z -> h (bf16 into A2 cols 0..511) -------------
__global__ __launch_bounds__(256) void k_gates(const float* __restrict__ z, const float* __restrict__ C0,
                                               const float* __restrict__ bl, u16* __restrict__ A2){
    int flat = blockIdx.x*256 + threadIdx.x;  // B*512
    int b = flat>>9, u = flat&511;
    const float* zb = z + (size_t)b*2048;
    float zi = zb[u]      + bl[u];
    float zf = zb[512+u]  + bl[512+u];
    float zg = zb[1024+u] + bl[1024+u];
    float zo = zb[1536+u] + bl[1536+u];
    float c  = sigm(zf)*C0[b*512+u] + sigm(zi)*tanhf(zg);
    float hv = sigm(zo)*tanhf(c);
    hv = fminf(fmaxf(hv,-20.f),20.f);
    A2[(size_t)b*576 + u] = f2bf(hv);
}

// ------------- GEMM 2: [rout|wout] = h @ Wt_h^T  (2048 x 268(pad 384), K=512) -------------
__global__ __launch_bounds__(256) void k_gemm_heads(const u16* __restrict__ A2, const u16* __restrict__ Wt,
                                                    const float* __restrict__ br, const float* __restrict__ bw,
                                                    float* __restrict__ rout, float* __restrict__ wout){
    __shared__ u16 Al[128*32], Bl[128*32];
    f4 acc[4][4];
    int bm = blockIdx.x*128, bn = blockIdx.y*128;
    gemm128(A2, 576, Wt, 512, bm, bn, 16, Al, Bl, acc);
    int lane = threadIdx.x&63, quad = lane>>4, l16 = lane&15, w = threadIdx.x>>6;
    int wr = w>>1, wc = w&1;
    #pragma unroll
    for(int i=0;i<4;i++){
        #pragma unroll
        for(int j=0;j<4;j++){
            int col = bn + wc*64 + j*16 + l16;
            if(col >= 268) continue;
            #pragma unroll
            for(int r=0;r<4;r++){
                int row = bm + wr*64 + i*16 + quad*4 + r;
                float v = acc[i][j][r];
                if(col < 70) rout[(size_t)row*70 + col]        = v + br[col];
                else         wout[(size_t)row*198 + (col-70)]  = v + bw[col-70];
            }
        }
    }
}

// ------------- GEMM 3: y = clip([h|R_t] @ Wt_o^T + bo)  (2048 x 512, K=576) -------------
__global__ __launch_bounds__(256) void k_gemm_out(const u16* __restrict__ A2, const u16* __restrict__ Wt,
                                                  const float* __restrict__ bo, float* __restrict__ y){
    __shared__ u16 Al[128*32], Bl[128*32];
    f4 acc[4][4];
    int bm = blockIdx.x*128, bn = blockIdx.y*128;
    gemm128(A2, 576, Wt, 576, bm, bn, 18, Al, Bl, acc);
    int lane = threadIdx.x&63, quad = lane>>4, l16 = lane&15, w = threadIdx.x>>6;
    int wr = w>>1, wc = w&1;
    #pragma unroll
    for(int i=0;i<4;i++){
        #pragma unroll
        for(int j=0;j<4;j++){
            int col = bn + wc*64 + j*16 + l16;
            float bias = bo[col];
            #pragma unroll
            for(int r=0;r<4;r++){
                int row = bm + wr*64 + i*16 + quad*4 + r;
                float v = acc[i][j][r] + bias;
                v = fminf(fmaxf(v,-20.f),20.f);
                y[(size_t)row*512 + col] = v;
            }
        }
    }
}

// ------------- K4: per-b fused addressing (both heads, parallel) + R_t + m_t -------------
// Restructured vs prior version:
//  - dual-head fused ip/mnorm loop (single LDS pass over m0 rows)
//  - shuffle-based block reductions (6 shfl_xor + 1 4-slot LDS combine) -> ~8 barriers total (was ~70)
//  - R_t accumulated inside the m_t streaming loop (deletes 64 scalar ds_read_u16/thread pass)
//  - wgrr buffer aliased: wg_s[2][256] during addressing, rred[8][64] during R_t reduce
// LDS = 39.1 KB -> 4 blocks/CU (unchanged).
__global__ __launch_bounds__(256) void k_addr(const float* __restrict__ m0, const float* __restrict__ A0,
                                              const float* __restrict__ rout, const float* __restrict__ wout,
                                              u16* __restrict__ A2,
                                              float* __restrict__ out_mt, float* __restrict__ out_rt,
                                              float* __restrict__ out_wr, float* __restrict__ out_ww){
    __shared__ u16   m0h[256*66];        // 33792 B, +2 u16 pad/row -> 2-way-free LDS banks
    __shared__ float kk_s[2][64];        // tanh(k), both heads
    __shared__ float knorm_s[2];
    __shared__ float sc[2][6];           // beta-sp, g, s0,s1,s2, gamma-sp
    __shared__ float wgrr[512];          // phase1: wg_s[2][256]; phase2: rred[8][64]
    __shared__ float wsel[2][256];
    __shared__ float dv[64], avv[64];
    __shared__ float wpart[4][6];        // per-wave reduce partials: max0,max1,sum0,sum1,wsum0,wsum1
    int tid = threadIdx.x, b = blockIdx.x;
    int lane = tid & 63, w = tid >> 6;

    // early independent global loads (hide latency under staging)
    float a0r = A0[b*256 + tid];
    float a1r = A0[524288 + b*256 + tid];

    // ---- stage m0 -> LDS bf16 (coalesced float4) ----
    const float* mb = m0 + (size_t)b*16384;
    #pragma unroll
    for(int i=0;i<16;i++){
        int e = i*1024 + tid*4;
        float4 v = *(const float4*)(mb + e);
        int n = e>>6, mc = e&63;
        unsigned* dst = (unsigned*)&m0h[n*66 + mc];
        dst[0] = packbf(v.x, v.y);
        dst[1] = packbf(v.z, v.w);
    }

    // ---- head scalars, one wave per job ----
    if(tid < 128){
        int hh = tid >> 6, m = lane;
        float kv = tanhf(hh ? wout[b*198 + m] : rout[b*70 + m]);
        kk_s[hh][m] = kv;
        float s2 = kv*kv;
        #pragma unroll
        for(int o=32;o>0;o>>=1) s2 += __shfl_xor(s2, o, 64);
        if(m == 0) knorm_s[hh] = sqrtf(s2);
    } else if(tid < 192){
        int hh = tid - 128;
        if(hh < 2){
            const float* hd = hh ? (wout + b*198) : (rout + b*70);
            sc[hh][0] = softplus_(hd[64]);
            sc[hh][1] = sigm(hd[65]);
            float e0=hd[66], e1=hd[67], e2=hd[68];
            float mx = fmaxf(e0, fmaxf(e1, e2));
            float x0=expf(e0-mx), x1=expf(e1-mx), x2=expf(e2-mx);
            float ssum = x0+x1+x2;
            sc[hh][2]=x0/ssum; sc[hh][3]=x1/ssum; sc[hh][4]=x2/ssum;
            sc[hh][5] = softplus_(hd[69]);
        }
    } else {
        int m = tid - 192;
        dv[m]  = sigm(wout[b*198 + 70 + m]);
        avv[m] = tanhf(wout[b*198 + 134 + m]);
    }
    __syncthreads();   // (1) staging + scalars visible

    // ---- dual-head ip + mnorm, single pass over own row ----
    float ip0=0.f, ip1=0.f, ssq=0.f;
    {
        const u16* row = &m0h[tid*66];
        const float2* k0p = (const float2*)kk_s[0];
        const float2* k1p = (const float2*)kk_s[1];
        #pragma unroll
        for(int m=0;m<64;m+=2){
            float v0,v1; bfpair(*(const unsigned*)&row[m], v0, v1);
            float2 ka = k0p[m>>1], kb = k1p[m>>1];
            ssq += v0*v0 + v1*v1;
            ip0 += v0*ka.x + v1*ka.y;
            ip1 += v0*kb.x + v1*kb.y;
        }
    }
    float mn = sqrtf(ssq);
    float K0 = ip0 / (knorm_s[0]*mn + 1e-8f);
    float K1 = ip1 / (knorm_s[1]*mn + 1e-8f);
    float e0 = sc[0][0]*K0, e1 = sc[1][0]*K1;

    // ---- softmax max (both heads): wave shuffle + 4-slot combine ----
    float mx0 = e0, mx1 = e1;
    #pragma unroll
    for(int o=32;o>0;o>>=1){ mx0 = fmaxf(mx0, __shfl_xor(mx0,o,64)); mx1 = fmaxf(mx1, __shfl_xor(mx1,o,64)); }
    if(lane == 0){ wpart[w][0] = mx0; wpart[w][1] = mx1; }
    __syncthreads();   // (2)
    mx0 = fmaxf(fmaxf(wpart[0][0],wpart[1][0]), fmaxf(wpart[2][0],wpart[3][0]));
    mx1 = fmaxf(fmaxf(wpart[0][1],wpart[1][1]), fmaxf(wpart[2][1],wpart[3][1]));
    float p0 = expf(e0-mx0), p1 = expf(e1-mx1);
    float s0 = p0, s1 = p1;
    #pragma unroll
    for(int o=32;o>0;o>>=1){ s0 += __shfl_xor(s0,o,64); s1 += __shfl_xor(s1,o,64); }
    if(lane == 0){ wpart[w][2] = s0; wpart[w][3] = s1; }
    __syncthreads();   // (3)
    s0 = wpart[0][2]+wpart[1][2]+wpart[2][2]+wpart[3][2];
    s1 = wpart[0][3]+wpart[1][3]+wpart[2][3]+wpart[3][3];
    float wc0 = p0/s0, wc1 = p1/s1;

    // ---- gate + shift-conv + sharpen (both heads) ----
    float g0 = sc[0][1], g1 = sc[1][1];
    float wg0 = g0*wc0 + (1.f-g0)*a0r;
    float wg1 = g1*wc1 + (1.f-g1)*a1r;
    wgrr[tid] = wg0; wgrr[256+tid] = wg1;
    __syncthreads();   // (4)
    int nm1 = (tid+255)&255, np1 = (tid+1)&255;
    float conv0 = sc[0][2]*wg0 + sc[0][3]*wgrr[nm1]     + sc[0][4]*wgrr[np1];
    float conv1 = sc[1][2]*wg1 + sc[1][3]*wgrr[256+nm1] + sc[1][4]*wgrr[256+np1];
    conv0 = fmaxf(conv0, 1e-35f);  conv1 = fmaxf(conv1, 1e-35f);
    float wsh0 = expf(sc[0][5]*logf(conv0));
    float wsh1 = expf(sc[1][5]*logf(conv1));
    float t0 = wsh0, t1 = wsh1;
    #pragma unroll
    for(int o=32;o>0;o>>=1){ t0 += __shfl_xor(t0,o,64); t1 += __shfl_xor(t1,o,64); }
    if(lane == 0){ wpart[w][4] = t0; wpart[w][5] = t1; }
    __syncthreads();   // (5)
    t0 = wpart[0][4]+wpart[1][4]+wpart[2][4]+wpart[3][4];
    t1 = wpart[0][5]+wpart[1][5]+wpart[2][5]+wpart[3][5];
    float w0 = wsh0/t0, w1 = wsh1/t1;
    wsel[0][tid] = w0; wsel[1][tid] = w1;
    out_wr[b*256 + tid] = w0;
    out_ww[b*256 + tid] = w1;
    __syncthreads();   // (6) wsel visible; wgrr (wg_s) dead -> reusable as rred

    // ---- m_t streaming + fused R_t partial accumulation ----
    // thread covers cols mc..mc+3 for n = i*16 + (tid>>4), i=0..15
    float r0=0.f, r1=0.f, r2=0.f, r3=0.f;
    {
        int mc = (tid&15)*4;
        float d0=dv[mc], d1=dv[mc+1], d2=dv[mc+2], d3=dv[mc+3];
        float A0v=avv[mc], A1v=avv[mc+1], A2v=avv[mc+2], A3v=avv[mc+3];
        float* outb = out_mt + (size_t)b*16384;
        #pragma unroll
        for(int i=0;i<16;i++){
            int e = i*1024 + tid*4;
            int n = i*16 + (tid>>4);
            float wwv = wsel[1][n], wrv = wsel[0][n];
            const unsigned* src = (const unsigned*)&m0h[n*66 + mc];
            float v0,v1,v2,v3;
            bfpair(src[0], v0, v1);
            bfpair(src[1], v2, v3);
            float4 o;
            o.x = v0*(1.f - wwv*d0) + wwv*A0v;
            o.y = v1*(1.f - wwv*d1) + wwv*A1v;
            o.z = v2*(1.f - wwv*d2) + wwv*A2v;
            o.w = v3*(1.f - wwv*d3) + wwv*A3v;
            *(float4*)(outb + e) = o;
            r0 += wrv*v0; r1 += wrv*v1; r2 += wrv*v2; r3 += wrv*v3;
        }
    }
    // ---- R_t reduce: 16 n-groups -> 8 (register add) -> 64 (tree over rred) ----
    {
        float* rred = wgrr;                 // [8][64]
        int g = tid>>4, mc = (tid&15)*4;
        if(g >= 8){
            rred[(g-8)*64 + mc]   = r0;
            rred[(g-8)*64 + mc+1] = r1;
            rred[(g-8)*64 + mc+2] = r2;
            rred[(g-8)*64 + mc+3] = r3;
        }
        __syncthreads();   // (7)
        if(g < 8){
            rred[g*64 + mc]   += r0;
            rred[g*64 + mc+1] += r1;
            rred[g*64 + mc+2] += r2;
            rred[g*64 + mc+3] += r3;
        }
        __syncthreads();   // (8)
        if(tid < 64){
            float rt = 0.f;
            #pragma unroll
            for(int g2=0; g2<8; g2++) rt += rred[g2*64 + tid];
            out_rt[b*64 + tid] = rt;
            A2[(size_t)b*576 + 512 + tid] = f2bf(rt);   // feed out-GEMM
        }
    }
}

extern "C" void kernel_launch(void* const* d_in, const int* in_sizes, int n_in,
                              void* d_out, int out_size, void* d_ws, size_t ws_size,
                              hipStream_t stream) {
    const float* x     = (const float*)d_in[0];
    const float* H0    = (const float*)d_in[1];
    const float* C0    = (const float*)d_in[2];
    const float* m0    = (const float*)d_in[3];
    const float* R0    = (const float*)d_in[4];
    const float* A0    = (const float*)d_in[5];
    const float* Wprep = (const float*)d_in[6];
    const float* bprep = (const float*)d_in[7];
    const float* Wx    = (const float*)d_in[8];
    const float* Wh    = (const float*)d_in[9];
    const float* bl    = (const float*)d_in[10];
    const float* Wr    = (const float*)d_in[11];
    const float* br    = (const float*)d_in[12];
    const float* Ww    = (const float*)d_in[13];
    const float* bw    = (const float*)d_in[14];
    const float* Wo    = (const float*)d_in[15];
    const float* bo    = (const float*)d_in[16];

    float* ws = (float*)d_ws;
    // all offsets in floats, 16B-aligned
    u16*   Wt_lstm = (u16*)(ws + 0);          // 2048*1056 u16 = 1,081,344 f
    u16*   Wt_h    = (u16*)(ws + 1081344);    // 384*512  u16 = 98,304 f
    u16*   Wt_o    = (u16*)(ws + 1179648);    // 512*576  u16 = 147,456 f
    u16*   Abuf    = (u16*)(ws + 1327104);    // 2048*1056 u16 = 1,081,344 f
    u16*   A2      = (u16*)(ws + 2408448);    // 2048*576 u16 = 589,824 f
    float* z       =        ws + 2998272;     // 2048*2048 f
    float* rout    =        ws + 7192576;     // 2048*70
    float* wout    =        ws + 7335936;     // 2048*198
    // total ~7.74M floats = 31 MB

    float* out    = (float*)d_out;
    float* out_y  = out;              // 1048576
    float* out_mt = out + 1048576;    // 33554432
    float* out_rt = out + 34603008;   // 131072
    float* out_wr = out + 34734080;   // 524288
    float* out_ww = out + 35258368;   // 524288

    hipLaunchKernelGGL(k_wt_lstm,  dim3(64,33), dim3(256), 0, stream, Wx, Wh, Wt_lstm);
    hipLaunchKernelGGL(k_wt_heads, dim3(12,16), dim3(256), 0, stream, Wr, Ww, Wt_h);
    hipLaunchKernelGGL(k_wt_out,   dim3(16,18), dim3(256), 0, stream, Wo, Wt_o);
    hipLaunchKernelGGL(k_abuild,   dim3(4096),  dim3(256), 0, stream, x, H0, R0, Wprep, bprep, Abuf);
    hipLaunchKernelGGL(k_gemm_lstm, dim3(16,16), dim3(256), 0, stream, Abuf, Wt_lstm, z);
    hipLaunchKernelGGL(k_gates,    dim3(4096),  dim3(256), 0, stream, z, C0, bl, A2);
    hipLaunchKernelGGL(k_gemm_heads, dim3(16,3), dim3(256), 0, stream, A2, Wt_h, br, bw, rout, wout);
    hipLaunchKernelGGL(k_addr,     dim3(2048),  dim3(256), 0, stream, m0, A0, rout, wout, A2,
                       out_mt, out_rt, out_wr, out_ww);
    hipLaunchKernelGGL(k_gemm_out, dim3(16,4),  dim3(256), 0, stream, A2, Wt_o, bo, out_y);
}